// Round 6
// baseline (324.825 us; speedup 1.0000x reference)
//
#include <hip/hip_runtime.h>
#include <limits.h>
#include <cstdint>

typedef __bf16 bf16_t;
typedef __attribute__((ext_vector_type(8))) __bf16 bf16x8;
typedef __attribute__((ext_vector_type(4))) float f32x4;
typedef __attribute__((ext_vector_type(2))) float f32x2;

#define CH 64     // edges per wave in edge_stream

// ---------------------------------------------------------------------------
// Pack all four 128x128 weight matrices -> MFMA B-frag order, one launch.
// packed[((kt*8+nt)*64+L)*8+j] = W[kt*32+(L>>4)*8+j][nt*16+(L&15)]
// ---------------------------------------------------------------------------
struct PackArgs {
  const float* W[4];
  bf16_t* P[4];
};

__global__ __launch_bounds__(256) void pack4_kernel(PackArgs args) {
  int idx = blockIdx.x * blockDim.x + threadIdx.x;   // 4 * 16384
  int which = idx >> 14;
  int r = idx & 16383;
  int j  = r & 7;
  int L  = (r >> 3) & 63;
  int nt = (r >> 9) & 7;
  int kt = r >> 12;
  int k = kt * 32 + (L >> 4) * 8 + j;
  int n = nt * 16 + (L & 15);
  args.P[which][r] = (bf16_t)args.W[which][(size_t)k * 128 + n];
}

// ---------------------------------------------------------------------------
// Y = X @ Wtop via bf16 MFMA. X is fp32 (converted in-register). Also zeroes
// pooled rows for this WG (fuses zero_kernel). 256t / 128 rows (R1-proven:
// this producer shape keeps edge_stream at its 72.5us floor; R5's 64t/32-row
// variant poisoned edge FETCH +60MB).
// ---------------------------------------------------------------------------
__global__ __launch_bounds__(256, 4) void yproj_f32(
    const float* __restrict__ X, const bf16_t* __restrict__ Wtpk,
    bf16_t* __restrict__ Ybf, float* __restrict__ pooled, int N)
{
  const int tid = threadIdx.x;
  const int base = blockIdx.x * 128;

  float4 z = make_float4(0.f, 0.f, 0.f, 0.f);
  #pragma unroll
  for (int i = 0; i < 16; ++i) {
    int idx = tid + i * 256;
    int row = base + (idx >> 5);
    if (row < N)
      reinterpret_cast<float4*>(pooled)[(size_t)row * 32 + (idx & 31)] = z;
  }

  const int lane = tid & 63;
  const int w    = tid >> 6;
  const int q    = lane >> 4;
  const int ln   = lane & 15;
  const int n0   = base + w * 32;

  int r0 = n0 + ln, r1 = n0 + 16 + ln;
  int r0c = (r0 < N) ? r0 : (N - 1);
  int r1c = (r1 < N) ? r1 : (N - 1);
  const float* x0 = X + (size_t)r0c * 128 + q * 8;
  const float* x1 = X + (size_t)r1c * 128 + q * 8;

  f32x4 acc[2][8];
  #pragma unroll
  for (int mt = 0; mt < 2; ++mt)
    #pragma unroll
    for (int nt = 0; nt < 8; ++nt)
      #pragma unroll
      for (int r = 0; r < 4; ++r) acc[mt][nt][r] = 0.f;

  const bf16x8* Wp = reinterpret_cast<const bf16x8*>(Wtpk);
  #pragma unroll
  for (int kt = 0; kt < 4; ++kt) {
    float4 f0a = *reinterpret_cast<const float4*>(x0 + kt * 32);
    float4 f0b = *reinterpret_cast<const float4*>(x0 + kt * 32 + 4);
    float4 f1a = *reinterpret_cast<const float4*>(x1 + kt * 32);
    float4 f1b = *reinterpret_cast<const float4*>(x1 + kt * 32 + 4);
    bf16x8 a0, a1;
    a0[0] = (bf16_t)f0a.x; a0[1] = (bf16_t)f0a.y; a0[2] = (bf16_t)f0a.z; a0[3] = (bf16_t)f0a.w;
    a0[4] = (bf16_t)f0b.x; a0[5] = (bf16_t)f0b.y; a0[6] = (bf16_t)f0b.z; a0[7] = (bf16_t)f0b.w;
    a1[0] = (bf16_t)f1a.x; a1[1] = (bf16_t)f1a.y; a1[2] = (bf16_t)f1a.z; a1[3] = (bf16_t)f1a.w;
    a1[4] = (bf16_t)f1b.x; a1[5] = (bf16_t)f1b.y; a1[6] = (bf16_t)f1b.z; a1[7] = (bf16_t)f1b.w;
    #pragma unroll
    for (int nt = 0; nt < 8; ++nt) {
      bf16x8 bfrag = Wp[(kt * 8 + nt) * 64 + lane];
      acc[0][nt] = __builtin_amdgcn_mfma_f32_16x16x32_bf16(a0, bfrag, acc[0][nt], 0, 0, 0);
      acc[1][nt] = __builtin_amdgcn_mfma_f32_16x16x32_bf16(a1, bfrag, acc[1][nt], 0, 0, 0);
    }
  }

  #pragma unroll
  for (int mt = 0; mt < 2; ++mt) {
    #pragma unroll
    for (int r = 0; r < 4; ++r) {
      int row = n0 + mt * 16 + q * 4 + r;
      if (row < N) {
        #pragma unroll
        for (int nt = 0; nt < 8; ++nt) {
          int col = nt * 16 + ln;
          Ybf[(size_t)row * 128 + col] = (bf16_t)acc[mt][nt][r];
        }
      }
    }
  }
}

// ---------------------------------------------------------------------------
// Same but X already bf16 (block 1: reads featsB_bf written by update_fdot).
// Also zeroes pooled for edge pass 2 (runs after update_fdot consumed it).
// ---------------------------------------------------------------------------
__global__ __launch_bounds__(256, 4) void yproj_bf16(
    const bf16_t* __restrict__ Xbf, const bf16_t* __restrict__ Wtpk,
    bf16_t* __restrict__ Ybf, float* __restrict__ pooled, int N)
{
  const int tid = threadIdx.x;
  const int base = blockIdx.x * 128;

  float4 z = make_float4(0.f, 0.f, 0.f, 0.f);
  #pragma unroll
  for (int i = 0; i < 16; ++i) {
    int idx = tid + i * 256;
    int row = base + (idx >> 5);
    if (row < N)
      reinterpret_cast<float4*>(pooled)[(size_t)row * 32 + (idx & 31)] = z;
  }

  const int lane = tid & 63;
  const int w    = tid >> 6;
  const int q    = lane >> 4;
  const int ln   = lane & 15;
  const int n0   = base + w * 32;

  int r0 = n0 + ln, r1 = n0 + 16 + ln;
  int r0c = (r0 < N) ? r0 : (N - 1);
  int r1c = (r1 < N) ? r1 : (N - 1);
  const bf16_t* x0 = Xbf + (size_t)r0c * 128 + q * 8;
  const bf16_t* x1 = Xbf + (size_t)r1c * 128 + q * 8;

  f32x4 acc[2][8];
  #pragma unroll
  for (int mt = 0; mt < 2; ++mt)
    #pragma unroll
    for (int nt = 0; nt < 8; ++nt)
      #pragma unroll
      for (int r = 0; r < 4; ++r) acc[mt][nt][r] = 0.f;

  const bf16x8* Wp = reinterpret_cast<const bf16x8*>(Wtpk);
  #pragma unroll
  for (int kt = 0; kt < 4; ++kt) {
    bf16x8 a0 = *reinterpret_cast<const bf16x8*>(x0 + kt * 32);
    bf16x8 a1 = *reinterpret_cast<const bf16x8*>(x1 + kt * 32);
    #pragma unroll
    for (int nt = 0; nt < 8; ++nt) {
      bf16x8 bfrag = Wp[(kt * 8 + nt) * 64 + lane];
      acc[0][nt] = __builtin_amdgcn_mfma_f32_16x16x32_bf16(a0, bfrag, acc[0][nt], 0, 0, 0);
      acc[1][nt] = __builtin_amdgcn_mfma_f32_16x16x32_bf16(a1, bfrag, acc[1][nt], 0, 0, 0);
    }
  }

  #pragma unroll
  for (int mt = 0; mt < 2; ++mt) {
    #pragma unroll
    for (int r = 0; r < 4; ++r) {
      int row = n0 + mt * 16 + q * 4 + r;
      if (row < N) {
        #pragma unroll
        for (int nt = 0; nt < 8; ++nt) {
          int col = nt * 16 + ln;
          Ybf[(size_t)row * 128 + col] = (bf16_t)acc[mt][nt][r];
        }
      }
    }
  }
}

// ---------------------------------------------------------------------------
// Edge pass (R1 variant, best measured 72.2us; latency x per-CU line-fill
// concurrency wall -- rounds 1-3 showed deeper pipelines don't move it).
// ---------------------------------------------------------------------------
__global__ __launch_bounds__(256) void edge_stream(
    const bf16_t* __restrict__ Y,        // N x 128 bf16
    const float* __restrict__ Wb,        // 132 x 128; rows 128..131 = Wbot
    const float* __restrict__ bb,        // 128
    const float* __restrict__ add_info,  // E x 4
    const int* __restrict__ nbr, const int* __restrict__ segs,
    float* __restrict__ pooled, int E)
{
  __shared__ float a_lds[1024];          // 4 waves * 64 edges * 4 floats = 4KB
  const int lane = threadIdx.x & 63;
  const int wv = __builtin_amdgcn_readfirstlane(threadIdx.x >> 6);  // SGPR
  const int e0 = (blockIdx.x * 4 + wv) * CH;                        // uniform
  if (e0 >= E) return;
  const int c0 = lane * 2;

  f32x2 wk[4];
  #pragma unroll
  for (int k = 0; k < 4; ++k) {
    wk[k].x = Wb[(size_t)(128 + k) * 128 + c0];
    wk[k].y = Wb[(size_t)(128 + k) * 128 + c0 + 1];
  }
  f32x2 bbv;
  bbv.x = bb[c0]; bbv.y = bb[c0 + 1];

  unsigned* pooled_u = reinterpret_cast<unsigned*>(pooled);
  f32x2 v; v.x = 0.f; v.y = 0.f;

  if (e0 + CH <= E) {
    // ---- chunk header ----
    float4 av = *reinterpret_cast<const float4*>(add_info + (size_t)e0 * 4 + lane * 4);
    int v_nbr = nbr[e0 + lane];
    int v_sg  = segs[e0 + lane];

    // segment-boundary ballot: bit i set iff segs[e0+i] != segs[e0+i-1]
    int sg_prev = __shfl_up(v_sg, 1);
    unsigned long long bmask = __ballot(v_sg != sg_prev) & ~1ull;
    int cur = __builtin_amdgcn_readlane(v_sg, 0);

    // ---- 4-buffer rotating pipeline, prefetch 3 groups ahead ----
    unsigned ybuf[4][8];
    #pragma unroll
    for (int p = 0; p < 3; ++p) {
      #pragma unroll
      for (int j = 0; j < 8; ++j) {
        int rn = __builtin_amdgcn_readlane(v_nbr, p * 8 + j);
        ybuf[p][j] = *((const unsigned*)(Y + (size_t)rn * 128) + lane);
      }
    }

    // LDS stage of add_info (wave-private, no barrier needed)
    *reinterpret_cast<float4*>(a_lds + wv * 256 + lane * 4) = av;

    #pragma unroll
    for (int g = 0; g < CH / 8; ++g) {
      // issue group g+3 first (into buffer (g+3)&3 != g&3)
      if (g + 3 < CH / 8) {
        #pragma unroll
        for (int j = 0; j < 8; ++j) {
          int rn = __builtin_amdgcn_readlane(v_nbr, (g + 3) * 8 + j);
          ybuf[(g + 3) & 3][j] = *((const unsigned*)(Y + (size_t)rn * 128) + lane);
        }
      }
      // compute group g
      #pragma unroll
      for (int j = 0; j < 8; ++j) {
        const int i = g * 8 + j;                              // constant
        if (bmask & (1ull << i)) {                            // SALU-only test
          if (v.x > 0.f) atomicMax(&pooled_u[(size_t)cur * 128 + c0], __float_as_uint(v.x));
          if (v.y > 0.f) atomicMax(&pooled_u[(size_t)cur * 128 + c0 + 1], __float_as_uint(v.y));
          v.x = 0.f; v.y = 0.f;
          cur = __builtin_amdgcn_readlane(v_sg, i);           // rare path only
        }
        unsigned yb = ybuf[g & 3][j];
        f32x2 y;
        y.x = __uint_as_float(yb << 16);
        y.y = __uint_as_float(yb & 0xffff0000u);
        // broadcast read: all lanes same address -> no bank conflict
        f32x4 a4 = *reinterpret_cast<const f32x4*>(a_lds + wv * 256 + i * 4);
        f32x2 t = bbv + a4[0] * wk[0];   // v_pk_fma_f32 chain
        t += a4[1] * wk[1];
        t += a4[2] * wk[2];
        t += a4[3] * wk[3];
        t += y;                           // v_pk_add_f32
        v = __builtin_elementwise_max(v, t);   // v_pk_max_f32
      }
    }
    if (v.x > 0.f) atomicMax(&pooled_u[(size_t)cur * 128 + c0], __float_as_uint(v.x));
    if (v.y > 0.f) atomicMax(&pooled_u[(size_t)cur * 128 + c0 + 1], __float_as_uint(v.y));
  } else {
    // ---- tail path ----
    int cur = segs[e0];
    const int rem = E - e0;
    for (int i = 0; i < rem; ++i) {
      const int e = e0 + i;
      int sg = segs[e];
      if (sg != cur) {
        if (v.x > 0.f) atomicMax(&pooled_u[(size_t)cur * 128 + c0], __float_as_uint(v.x));
        if (v.y > 0.f) atomicMax(&pooled_u[(size_t)cur * 128 + c0 + 1], __float_as_uint(v.y));
        v.x = 0.f; v.y = 0.f; cur = sg;
      }
      unsigned yb = *reinterpret_cast<const unsigned*>(Y + (size_t)nbr[e] * 128 + c0);
      float y0 = __uint_as_float(yb << 16);
      float y1 = __uint_as_float(yb & 0xffff0000u);
      const float* ai = add_info + (size_t)e * 4;
      float a0 = ai[0], a1 = ai[1], a2 = ai[2], a3 = ai[3];
      float t0 = y0 + bbv.x + a0 * wk[0].x + a1 * wk[1].x + a2 * wk[2].x + a3 * wk[3].x;
      float t1 = y1 + bbv.y + a0 * wk[0].y + a1 * wk[1].y + a2 * wk[2].y + a3 * wk[3].y;
      v.x = fmaxf(v.x, t0);
      v.y = fmaxf(v.y, t1);
    }
    if (v.x > 0.f) atomicMax(&pooled_u[(size_t)cur * 128 + c0], __float_as_uint(v.x));
    if (v.y > 0.f) atomicMax(&pooled_u[(size_t)cur * 128 + c0 + 1], __float_as_uint(v.y));
  }
}

// ---------------------------------------------------------------------------
// Block-0 update with fdot linearization:
//   featsB  = featsIn + pooled @ Wo0 + bo0   (registers only)
//   featsB_bf = bf16(featsB)                 (12.8MB -- feeds yproj_bf16)
//   fdot[n] = featsB[n] . Wf                 (0.2MB -- replaces the 25.6MB
//                                             f32 featsB round trip, since
//                                             out = featsB.Wf + (...).Wf + bf)
// ---------------------------------------------------------------------------
__global__ __launch_bounds__(256, 4) void update_fdot(
    const float* __restrict__ featsIn, const float* __restrict__ pooled,
    const bf16_t* __restrict__ Wopk, const float* __restrict__ bo,
    const float* __restrict__ Wf,
    bf16_t* __restrict__ featsOutBf, float* __restrict__ fdot, int N)
{
  const int tid  = threadIdx.x;
  const int lane = tid & 63;
  const int w    = tid >> 6;
  const int q    = lane >> 4;
  const int ln   = lane & 15;
  const int n0   = blockIdx.x * 128 + w * 32;

  int r0 = n0 + ln, r1 = n0 + 16 + ln;
  int r0c = (r0 < N) ? r0 : (N - 1);
  int r1c = (r1 < N) ? r1 : (N - 1);
  const float* p0 = pooled + (size_t)r0c * 128 + q * 8;
  const float* p1 = pooled + (size_t)r1c * 128 + q * 8;

  f32x4 acc[2][8];
  #pragma unroll
  for (int mt = 0; mt < 2; ++mt)
    #pragma unroll
    for (int nt = 0; nt < 8; ++nt)
      #pragma unroll
      for (int r = 0; r < 4; ++r) acc[mt][nt][r] = 0.f;

  const bf16x8* Wp = reinterpret_cast<const bf16x8*>(Wopk);
  #pragma unroll
  for (int kt = 0; kt < 4; ++kt) {
    float4 f0a = *reinterpret_cast<const float4*>(p0 + kt * 32);
    float4 f0b = *reinterpret_cast<const float4*>(p0 + kt * 32 + 4);
    float4 f1a = *reinterpret_cast<const float4*>(p1 + kt * 32);
    float4 f1b = *reinterpret_cast<const float4*>(p1 + kt * 32 + 4);
    bf16x8 a0, a1;
    a0[0] = (bf16_t)f0a.x; a0[1] = (bf16_t)f0a.y; a0[2] = (bf16_t)f0a.z; a0[3] = (bf16_t)f0a.w;
    a0[4] = (bf16_t)f0b.x; a0[5] = (bf16_t)f0b.y; a0[6] = (bf16_t)f0b.z; a0[7] = (bf16_t)f0b.w;
    a1[0] = (bf16_t)f1a.x; a1[1] = (bf16_t)f1a.y; a1[2] = (bf16_t)f1a.z; a1[3] = (bf16_t)f1a.w;
    a1[4] = (bf16_t)f1b.x; a1[5] = (bf16_t)f1b.y; a1[6] = (bf16_t)f1b.z; a1[7] = (bf16_t)f1b.w;
    #pragma unroll
    for (int nt = 0; nt < 8; ++nt) {
      bf16x8 bfrag = Wp[(kt * 8 + nt) * 64 + lane];
      acc[0][nt] = __builtin_amdgcn_mfma_f32_16x16x32_bf16(a0, bfrag, acc[0][nt], 0, 0, 0);
      acc[1][nt] = __builtin_amdgcn_mfma_f32_16x16x32_bf16(a1, bfrag, acc[1][nt], 0, 0, 0);
    }
  }

  float bov[8], wfv[8];
  #pragma unroll
  for (int nt = 0; nt < 8; ++nt) { bov[nt] = bo[nt * 16 + ln]; wfv[nt] = Wf[nt * 16 + ln]; }

  #pragma unroll
  for (int mt = 0; mt < 2; ++mt) {
    #pragma unroll
    for (int r = 0; r < 4; ++r) {
      int row = n0 + mt * 16 + q * 4 + r;
      float partial = 0.f;
      if (row < N) {
        #pragma unroll
        for (int nt = 0; nt < 8; ++nt) {
          int col = nt * 16 + ln;
          float o = featsIn[(size_t)row * 128 + col] + acc[mt][nt][r] + bov[nt];
          featsOutBf[(size_t)row * 128 + col] = (bf16_t)o;
          partial += o * wfv[nt];
        }
      }
      partial += __shfl_xor(partial, 1);
      partial += __shfl_xor(partial, 2);
      partial += __shfl_xor(partial, 4);
      partial += __shfl_xor(partial, 8);
      if (ln == 0 && row < N) fdot[row] = partial;
    }
  }
}

// ---------------------------------------------------------------------------
// Block-1 update + final projection, fdot form (no featsB input):
// out[n] = fdot[n] + (pooled[n] @ Wo1 + bo1) . Wf + bf
// ---------------------------------------------------------------------------
__global__ __launch_bounds__(256, 4) void update_final_mfma(
    const float* __restrict__ fdot, const float* __restrict__ pooled,
    const bf16_t* __restrict__ Wopk, const float* __restrict__ bo,
    const float* __restrict__ Wf, const float* __restrict__ bf_,
    float* __restrict__ out, int N)
{
  const int tid  = threadIdx.x;
  const int lane = tid & 63;
  const int w    = tid >> 6;
  const int q    = lane >> 4;
  const int ln   = lane & 15;
  const int n0   = blockIdx.x * 128 + w * 32;

  int r0 = n0 + ln, r1 = n0 + 16 + ln;
  int r0c = (r0 < N) ? r0 : (N - 1);
  int r1c = (r1 < N) ? r1 : (N - 1);
  const float* p0 = pooled + (size_t)r0c * 128 + q * 8;
  const float* p1 = pooled + (size_t)r1c * 128 + q * 8;

  f32x4 acc[2][8];
  #pragma unroll
  for (int mt = 0; mt < 2; ++mt)
    #pragma unroll
    for (int nt = 0; nt < 8; ++nt)
      #pragma unroll
      for (int r = 0; r < 4; ++r) acc[mt][nt][r] = 0.f;

  const bf16x8* Wp = reinterpret_cast<const bf16x8*>(Wopk);
  #pragma unroll
  for (int kt = 0; kt < 4; ++kt) {
    float4 f0a = *reinterpret_cast<const float4*>(p0 + kt * 32);
    float4 f0b = *reinterpret_cast<const float4*>(p0 + kt * 32 + 4);
    float4 f1a = *reinterpret_cast<const float4*>(p1 + kt * 32);
    float4 f1b = *reinterpret_cast<const float4*>(p1 + kt * 32 + 4);
    bf16x8 a0, a1;
    a0[0] = (bf16_t)f0a.x; a0[1] = (bf16_t)f0a.y; a0[2] = (bf16_t)f0a.z; a0[3] = (bf16_t)f0a.w;
    a0[4] = (bf16_t)f0b.x; a0[5] = (bf16_t)f0b.y; a0[6] = (bf16_t)f0b.z; a0[7] = (bf16_t)f0b.w;
    a1[0] = (bf16_t)f1a.x; a1[1] = (bf16_t)f1a.y; a1[2] = (bf16_t)f1a.z; a1[3] = (bf16_t)f1a.w;
    a1[4] = (bf16_t)f1b.x; a1[5] = (bf16_t)f1b.y; a1[6] = (bf16_t)f1b.z; a1[7] = (bf16_t)f1b.w;
    #pragma unroll
    for (int nt = 0; nt < 8; ++nt) {
      bf16x8 bfrag = Wp[(kt * 8 + nt) * 64 + lane];
      acc[0][nt] = __builtin_amdgcn_mfma_f32_16x16x32_bf16(a0, bfrag, acc[0][nt], 0, 0, 0);
      acc[1][nt] = __builtin_amdgcn_mfma_f32_16x16x32_bf16(a1, bfrag, acc[1][nt], 0, 0, 0);
    }
  }

  float bov[8], wfv[8];
  #pragma unroll
  for (int nt = 0; nt < 8; ++nt) { bov[nt] = bo[nt * 16 + ln]; wfv[nt] = Wf[nt * 16 + ln]; }
  float bfs = bf_[0];

  #pragma unroll
  for (int mt = 0; mt < 2; ++mt) {
    #pragma unroll
    for (int r = 0; r < 4; ++r) {
      int row = n0 + mt * 16 + q * 4 + r;
      float partial = 0.f;
      #pragma unroll
      for (int nt = 0; nt < 8; ++nt)
        partial += (acc[mt][nt][r] + bov[nt]) * wfv[nt];
      partial += __shfl_xor(partial, 1);
      partial += __shfl_xor(partial, 2);
      partial += __shfl_xor(partial, 4);
      partial += __shfl_xor(partial, 8);
      if (ln == 0 && row < N) out[row] = partial + fdot[row] + bfs;
    }
  }
}

// ---------------------------------------------------------------------------
extern "C" void kernel_launch(void* const* d_in, const int* in_sizes, int n_in,
                              void* d_out, int out_size, void* d_ws, size_t ws_size,
                              hipStream_t stream)
{
  const float* interpolated = (const float*)d_in[0];
  const float* add_info     = (const float*)d_in[1];
  const int*   nbr          = (const int*)d_in[2];
  const int*   segs         = (const int*)d_in[3];
  const float* Wb0 = (const float*)d_in[4];
  const float* bb0 = (const float*)d_in[5];
  const float* Wo0 = (const float*)d_in[6];
  const float* bo0 = (const float*)d_in[7];
  const float* Wb1 = (const float*)d_in[8];
  const float* bb1 = (const float*)d_in[9];
  const float* Wo1 = (const float*)d_in[10];
  const float* bo1 = (const float*)d_in[11];
  const float* Wf  = (const float*)d_in[12];
  const float* bf_ = (const float*)d_in[13];

  const int N = in_sizes[0] / 128;
  const int E = in_sizes[2];
  float* out = (float*)d_out;

  // workspace layout
  float* pooled = (float*)d_ws;                              // N*128 f32
  float* fdot   = pooled + (size_t)N * 128;                  // N f32
  bf16_t* featsB_bf = (bf16_t*)(fdot + N);                   // N*128 bf16
  bf16_t* Ybf       = featsB_bf + (size_t)N * 128;           // N*128 bf16
  bf16_t* Wtpk0 = Ybf + (size_t)N * 128;                     // 16384
  bf16_t* Wtpk1 = Wtpk0 + 16384;
  bf16_t* Wopk0 = Wtpk1 + 16384;
  bf16_t* Wopk1 = Wopk0 + 16384;

  const int ugrid = (N + 127) / 128;
  const int egrid = (E + CH * 4 - 1) / (CH * 4);

  // single pack launch for all four 128x128 weights (Wb top rows 0..127, Wo)
  PackArgs pa;
  pa.W[0] = Wb0; pa.P[0] = Wtpk0;
  pa.W[1] = Wb1; pa.P[1] = Wtpk1;
  pa.W[2] = Wo0; pa.P[2] = Wopk0;
  pa.W[3] = Wo1; pa.P[3] = Wopk1;
  pack4_kernel<<<256, 256, 0, stream>>>(pa);

  // block 0
  yproj_f32<<<ugrid, 256, 0, stream>>>(interpolated, Wtpk0, Ybf, pooled, N);
  edge_stream<<<egrid, 256, 0, stream>>>(Ybf, Wb0, bb0, add_info, nbr, segs,
                                         pooled, E);
  update_fdot<<<ugrid, 256, 0, stream>>>(interpolated, pooled, Wopk0, bo0,
                                         Wf, featsB_bf, fdot, N);

  // block 1
  yproj_bf16<<<ugrid, 256, 0, stream>>>(featsB_bf, Wtpk1, Ybf, pooled, N);
  edge_stream<<<egrid, 256, 0, stream>>>(Ybf, Wb1, bb1, add_info, nbr, segs,
                                         pooled, E);
  update_final_mfma<<<ugrid, 256, 0, stream>>>(fdot, pooled, Wopk1, bo1,
                                               Wf, bf_, out, N);
}

// Round 7
// 305.166 us; speedup vs baseline: 1.0644x; 1.0644x over previous
//
#include <hip/hip_runtime.h>
#include <limits.h>
#include <cstdint>

typedef __bf16 bf16_t;
typedef __attribute__((ext_vector_type(8))) __bf16 bf16x8;
typedef __attribute__((ext_vector_type(4))) float f32x4;
typedef __attribute__((ext_vector_type(2))) float f32x2;

#define CH 64     // edges per wave in edge_stream

// ---------------------------------------------------------------------------
// Pack all four 128x128 weight matrices -> MFMA B-frag order, one launch.
// packed[((kt*8+nt)*64+L)*8+j] = W[kt*32+(L>>4)*8+j][nt*16+(L&15)]
// ---------------------------------------------------------------------------
struct PackArgs {
  const float* W[4];
  bf16_t* P[4];
};

__global__ __launch_bounds__(256) void pack4_kernel(PackArgs args) {
  int idx = blockIdx.x * blockDim.x + threadIdx.x;   // 4 * 16384
  int which = idx >> 14;
  int r = idx & 16383;
  int j  = r & 7;
  int L  = (r >> 3) & 63;
  int nt = (r >> 9) & 7;
  int kt = r >> 12;
  int k = kt * 32 + (L >> 4) * 8 + j;
  int n = nt * 16 + (L & 15);
  args.P[which][r] = (bf16_t)args.W[which][(size_t)k * 128 + n];
}

// ---------------------------------------------------------------------------
// Y = X @ Wtop via bf16 MFMA. X is fp32 (converted in-register). Also zeroes
// pooled rows for this WG (fuses zero_kernel).
// ---------------------------------------------------------------------------
__global__ __launch_bounds__(256, 4) void yproj_f32(
    const float* __restrict__ X, const bf16_t* __restrict__ Wtpk,
    bf16_t* __restrict__ Ybf, float* __restrict__ pooled, int N)
{
  const int tid = threadIdx.x;
  const int base = blockIdx.x * 128;

  float4 z = make_float4(0.f, 0.f, 0.f, 0.f);
  #pragma unroll
  for (int i = 0; i < 16; ++i) {
    int idx = tid + i * 256;
    int row = base + (idx >> 5);
    if (row < N)
      reinterpret_cast<float4*>(pooled)[(size_t)row * 32 + (idx & 31)] = z;
  }

  const int lane = tid & 63;
  const int w    = tid >> 6;
  const int q    = lane >> 4;
  const int ln   = lane & 15;
  const int n0   = base + w * 32;

  int r0 = n0 + ln, r1 = n0 + 16 + ln;
  int r0c = (r0 < N) ? r0 : (N - 1);
  int r1c = (r1 < N) ? r1 : (N - 1);
  const float* x0 = X + (size_t)r0c * 128 + q * 8;
  const float* x1 = X + (size_t)r1c * 128 + q * 8;

  f32x4 acc[2][8];
  #pragma unroll
  for (int mt = 0; mt < 2; ++mt)
    #pragma unroll
    for (int nt = 0; nt < 8; ++nt)
      #pragma unroll
      for (int r = 0; r < 4; ++r) acc[mt][nt][r] = 0.f;

  const bf16x8* Wp = reinterpret_cast<const bf16x8*>(Wtpk);
  #pragma unroll
  for (int kt = 0; kt < 4; ++kt) {
    float4 f0a = *reinterpret_cast<const float4*>(x0 + kt * 32);
    float4 f0b = *reinterpret_cast<const float4*>(x0 + kt * 32 + 4);
    float4 f1a = *reinterpret_cast<const float4*>(x1 + kt * 32);
    float4 f1b = *reinterpret_cast<const float4*>(x1 + kt * 32 + 4);
    bf16x8 a0, a1;
    a0[0] = (bf16_t)f0a.x; a0[1] = (bf16_t)f0a.y; a0[2] = (bf16_t)f0a.z; a0[3] = (bf16_t)f0a.w;
    a0[4] = (bf16_t)f0b.x; a0[5] = (bf16_t)f0b.y; a0[6] = (bf16_t)f0b.z; a0[7] = (bf16_t)f0b.w;
    a1[0] = (bf16_t)f1a.x; a1[1] = (bf16_t)f1a.y; a1[2] = (bf16_t)f1a.z; a1[3] = (bf16_t)f1a.w;
    a1[4] = (bf16_t)f1b.x; a1[5] = (bf16_t)f1b.y; a1[6] = (bf16_t)f1b.z; a1[7] = (bf16_t)f1b.w;
    #pragma unroll
    for (int nt = 0; nt < 8; ++nt) {
      bf16x8 bfrag = Wp[(kt * 8 + nt) * 64 + lane];
      acc[0][nt] = __builtin_amdgcn_mfma_f32_16x16x32_bf16(a0, bfrag, acc[0][nt], 0, 0, 0);
      acc[1][nt] = __builtin_amdgcn_mfma_f32_16x16x32_bf16(a1, bfrag, acc[1][nt], 0, 0, 0);
    }
  }

  #pragma unroll
  for (int mt = 0; mt < 2; ++mt) {
    #pragma unroll
    for (int r = 0; r < 4; ++r) {
      int row = n0 + mt * 16 + q * 4 + r;
      if (row < N) {
        #pragma unroll
        for (int nt = 0; nt < 8; ++nt) {
          int col = nt * 16 + ln;
          Ybf[(size_t)row * 128 + col] = (bf16_t)acc[mt][nt][r];
        }
      }
    }
  }
}

// ---------------------------------------------------------------------------
// Same but X already bf16 (block 1: reads featsB_bf written by update_mfma).
// Also zeroes pooled for edge pass 2.
// ---------------------------------------------------------------------------
__global__ __launch_bounds__(256, 4) void yproj_bf16(
    const bf16_t* __restrict__ Xbf, const bf16_t* __restrict__ Wtpk,
    bf16_t* __restrict__ Ybf, float* __restrict__ pooled, int N)
{
  const int tid = threadIdx.x;
  const int base = blockIdx.x * 128;

  float4 z = make_float4(0.f, 0.f, 0.f, 0.f);
  #pragma unroll
  for (int i = 0; i < 16; ++i) {
    int idx = tid + i * 256;
    int row = base + (idx >> 5);
    if (row < N)
      reinterpret_cast<float4*>(pooled)[(size_t)row * 32 + (idx & 31)] = z;
  }

  const int lane = tid & 63;
  const int w    = tid >> 6;
  const int q    = lane >> 4;
  const int ln   = lane & 15;
  const int n0   = base + w * 32;

  int r0 = n0 + ln, r1 = n0 + 16 + ln;
  int r0c = (r0 < N) ? r0 : (N - 1);
  int r1c = (r1 < N) ? r1 : (N - 1);
  const bf16_t* x0 = Xbf + (size_t)r0c * 128 + q * 8;
  const bf16_t* x1 = Xbf + (size_t)r1c * 128 + q * 8;

  f32x4 acc[2][8];
  #pragma unroll
  for (int mt = 0; mt < 2; ++mt)
    #pragma unroll
    for (int nt = 0; nt < 8; ++nt)
      #pragma unroll
      for (int r = 0; r < 4; ++r) acc[mt][nt][r] = 0.f;

  const bf16x8* Wp = reinterpret_cast<const bf16x8*>(Wtpk);
  #pragma unroll
  for (int kt = 0; kt < 4; ++kt) {
    bf16x8 a0 = *reinterpret_cast<const bf16x8*>(x0 + kt * 32);
    bf16x8 a1 = *reinterpret_cast<const bf16x8*>(x1 + kt * 32);
    #pragma unroll
    for (int nt = 0; nt < 8; ++nt) {
      bf16x8 bfrag = Wp[(kt * 8 + nt) * 64 + lane];
      acc[0][nt] = __builtin_amdgcn_mfma_f32_16x16x32_bf16(a0, bfrag, acc[0][nt], 0, 0, 0);
      acc[1][nt] = __builtin_amdgcn_mfma_f32_16x16x32_bf16(a1, bfrag, acc[1][nt], 0, 0, 0);
    }
  }

  #pragma unroll
  for (int mt = 0; mt < 2; ++mt) {
    #pragma unroll
    for (int r = 0; r < 4; ++r) {
      int row = n0 + mt * 16 + q * 4 + r;
      if (row < N) {
        #pragma unroll
        for (int nt = 0; nt < 8; ++nt) {
          int col = nt * 16 + ln;
          Ybf[(size_t)row * 128 + col] = (bf16_t)acc[mt][nt][r];
        }
      }
    }
  }
}

// ---------------------------------------------------------------------------
// Edge pass (R1 variant, best measured 72.1us; latency x per-CU line-fill
// concurrency wall -- rounds 1-3 showed deeper pipelines don't move it).
// ---------------------------------------------------------------------------
__global__ __launch_bounds__(256) void edge_stream(
    const bf16_t* __restrict__ Y,        // N x 128 bf16
    const float* __restrict__ Wb,        // 132 x 128; rows 128..131 = Wbot
    const float* __restrict__ bb,        // 128
    const float* __restrict__ add_info,  // E x 4
    const int* __restrict__ nbr, const int* __restrict__ segs,
    float* __restrict__ pooled, int E)
{
  __shared__ float a_lds[1024];          // 4 waves * 64 edges * 4 floats = 4KB
  const int lane = threadIdx.x & 63;
  const int wv = __builtin_amdgcn_readfirstlane(threadIdx.x >> 6);  // SGPR
  const int e0 = (blockIdx.x * 4 + wv) * CH;                        // uniform
  if (e0 >= E) return;
  const int c0 = lane * 2;

  f32x2 wk[4];
  #pragma unroll
  for (int k = 0; k < 4; ++k) {
    wk[k].x = Wb[(size_t)(128 + k) * 128 + c0];
    wk[k].y = Wb[(size_t)(128 + k) * 128 + c0 + 1];
  }
  f32x2 bbv;
  bbv.x = bb[c0]; bbv.y = bb[c0 + 1];

  unsigned* pooled_u = reinterpret_cast<unsigned*>(pooled);
  f32x2 v; v.x = 0.f; v.y = 0.f;

  if (e0 + CH <= E) {
    // ---- chunk header ----
    float4 av = *reinterpret_cast<const float4*>(add_info + (size_t)e0 * 4 + lane * 4);
    int v_nbr = nbr[e0 + lane];
    int v_sg  = segs[e0 + lane];

    // segment-boundary ballot: bit i set iff segs[e0+i] != segs[e0+i-1]
    int sg_prev = __shfl_up(v_sg, 1);
    unsigned long long bmask = __ballot(v_sg != sg_prev) & ~1ull;
    int cur = __builtin_amdgcn_readlane(v_sg, 0);

    // ---- 4-buffer rotating pipeline, prefetch 3 groups ahead ----
    unsigned ybuf[4][8];
    #pragma unroll
    for (int p = 0; p < 3; ++p) {
      #pragma unroll
      for (int j = 0; j < 8; ++j) {
        int rn = __builtin_amdgcn_readlane(v_nbr, p * 8 + j);
        ybuf[p][j] = *((const unsigned*)(Y + (size_t)rn * 128) + lane);
      }
    }

    // LDS stage of add_info (wave-private, no barrier needed)
    *reinterpret_cast<float4*>(a_lds + wv * 256 + lane * 4) = av;

    #pragma unroll
    for (int g = 0; g < CH / 8; ++g) {
      // issue group g+3 first (into buffer (g+3)&3 != g&3)
      if (g + 3 < CH / 8) {
        #pragma unroll
        for (int j = 0; j < 8; ++j) {
          int rn = __builtin_amdgcn_readlane(v_nbr, (g + 3) * 8 + j);
          ybuf[(g + 3) & 3][j] = *((const unsigned*)(Y + (size_t)rn * 128) + lane);
        }
      }
      // compute group g
      #pragma unroll
      for (int j = 0; j < 8; ++j) {
        const int i = g * 8 + j;                              // constant
        if (bmask & (1ull << i)) {                            // SALU-only test
          if (v.x > 0.f) atomicMax(&pooled_u[(size_t)cur * 128 + c0], __float_as_uint(v.x));
          if (v.y > 0.f) atomicMax(&pooled_u[(size_t)cur * 128 + c0 + 1], __float_as_uint(v.y));
          v.x = 0.f; v.y = 0.f;
          cur = __builtin_amdgcn_readlane(v_sg, i);           // rare path only
        }
        unsigned yb = ybuf[g & 3][j];
        f32x2 y;
        y.x = __uint_as_float(yb << 16);
        y.y = __uint_as_float(yb & 0xffff0000u);
        // broadcast read: all lanes same address -> no bank conflict
        f32x4 a4 = *reinterpret_cast<const f32x4*>(a_lds + wv * 256 + i * 4);
        f32x2 t = bbv + a4[0] * wk[0];   // v_pk_fma_f32 chain
        t += a4[1] * wk[1];
        t += a4[2] * wk[2];
        t += a4[3] * wk[3];
        t += y;                           // v_pk_add_f32
        v = __builtin_elementwise_max(v, t);   // v_pk_max_f32
      }
    }
    if (v.x > 0.f) atomicMax(&pooled_u[(size_t)cur * 128 + c0], __float_as_uint(v.x));
    if (v.y > 0.f) atomicMax(&pooled_u[(size_t)cur * 128 + c0 + 1], __float_as_uint(v.y));
  } else {
    // ---- tail path ----
    int cur = segs[e0];
    const int rem = E - e0;
    for (int i = 0; i < rem; ++i) {
      const int e = e0 + i;
      int sg = segs[e];
      if (sg != cur) {
        if (v.x > 0.f) atomicMax(&pooled_u[(size_t)cur * 128 + c0], __float_as_uint(v.x));
        if (v.y > 0.f) atomicMax(&pooled_u[(size_t)cur * 128 + c0 + 1], __float_as_uint(v.y));
        v.x = 0.f; v.y = 0.f; cur = sg;
      }
      unsigned yb = *reinterpret_cast<const unsigned*>(Y + (size_t)nbr[e] * 128 + c0);
      float y0 = __uint_as_float(yb << 16);
      float y1 = __uint_as_float(yb & 0xffff0000u);
      const float* ai = add_info + (size_t)e * 4;
      float a0 = ai[0], a1 = ai[1], a2 = ai[2], a3 = ai[3];
      float t0 = y0 + bbv.x + a0 * wk[0].x + a1 * wk[1].x + a2 * wk[2].x + a3 * wk[3].x;
      float t1 = y1 + bbv.y + a0 * wk[0].y + a1 * wk[1].y + a2 * wk[2].y + a3 * wk[3].y;
      v.x = fmaxf(v.x, t0);
      v.y = fmaxf(v.y, t1);
    }
    if (v.x > 0.f) atomicMax(&pooled_u[(size_t)cur * 128 + c0], __float_as_uint(v.x));
    if (v.y > 0.f) atomicMax(&pooled_u[(size_t)cur * 128 + c0 + 1], __float_as_uint(v.y));
  }
}

// ---------------------------------------------------------------------------
// Block-0 update (R0 form, featsB f32 write KEPT -- empirical guard: rounds
// 5/6 showed dropping this write costs edge_stream +60MB FETCH / +12us x2)
// plus fdot computed while featsB is live in registers:
//   featsB    = featsIn + pooled @ Wo0 + bo0    (f32 write, 25.6MB)
//   featsB_bf = bf16(featsB)                    (12.8MB, feeds yproj_bf16)
//   fdot[n]   = featsB[n] . Wf                  (0.2MB; lets update_final
//                                                skip the 25.6MB featsB read)
// ---------------------------------------------------------------------------
__global__ __launch_bounds__(256, 4) void update_mfma(
    const float* __restrict__ featsIn, const float* __restrict__ pooled,
    const bf16_t* __restrict__ Wopk, const float* __restrict__ bo,
    const float* __restrict__ Wf,
    float* __restrict__ featsOut, bf16_t* __restrict__ featsOutBf,
    float* __restrict__ fdot, int N)
{
  const int tid  = threadIdx.x;
  const int lane = tid & 63;
  const int w    = tid >> 6;
  const int q    = lane >> 4;
  const int ln   = lane & 15;
  const int n0   = blockIdx.x * 128 + w * 32;

  int r0 = n0 + ln, r1 = n0 + 16 + ln;
  int r0c = (r0 < N) ? r0 : (N - 1);
  int r1c = (r1 < N) ? r1 : (N - 1);
  const float* p0 = pooled + (size_t)r0c * 128 + q * 8;
  const float* p1 = pooled + (size_t)r1c * 128 + q * 8;

  f32x4 acc[2][8];
  #pragma unroll
  for (int mt = 0; mt < 2; ++mt)
    #pragma unroll
    for (int nt = 0; nt < 8; ++nt)
      #pragma unroll
      for (int r = 0; r < 4; ++r) acc[mt][nt][r] = 0.f;

  const bf16x8* Wp = reinterpret_cast<const bf16x8*>(Wopk);
  #pragma unroll
  for (int kt = 0; kt < 4; ++kt) {
    float4 f0a = *reinterpret_cast<const float4*>(p0 + kt * 32);
    float4 f0b = *reinterpret_cast<const float4*>(p0 + kt * 32 + 4);
    float4 f1a = *reinterpret_cast<const float4*>(p1 + kt * 32);
    float4 f1b = *reinterpret_cast<const float4*>(p1 + kt * 32 + 4);
    bf16x8 a0, a1;
    a0[0] = (bf16_t)f0a.x; a0[1] = (bf16_t)f0a.y; a0[2] = (bf16_t)f0a.z; a0[3] = (bf16_t)f0a.w;
    a0[4] = (bf16_t)f0b.x; a0[5] = (bf16_t)f0b.y; a0[6] = (bf16_t)f0b.z; a0[7] = (bf16_t)f0b.w;
    a1[0] = (bf16_t)f1a.x; a1[1] = (bf16_t)f1a.y; a1[2] = (bf16_t)f1a.z; a1[3] = (bf16_t)f1a.w;
    a1[4] = (bf16_t)f1b.x; a1[5] = (bf16_t)f1b.y; a1[6] = (bf16_t)f1b.z; a1[7] = (bf16_t)f1b.w;
    #pragma unroll
    for (int nt = 0; nt < 8; ++nt) {
      bf16x8 bfrag = Wp[(kt * 8 + nt) * 64 + lane];
      acc[0][nt] = __builtin_amdgcn_mfma_f32_16x16x32_bf16(a0, bfrag, acc[0][nt], 0, 0, 0);
      acc[1][nt] = __builtin_amdgcn_mfma_f32_16x16x32_bf16(a1, bfrag, acc[1][nt], 0, 0, 0);
    }
  }

  float bov[8], wfv[8];
  #pragma unroll
  for (int nt = 0; nt < 8; ++nt) { bov[nt] = bo[nt * 16 + ln]; wfv[nt] = Wf[nt * 16 + ln]; }

  #pragma unroll
  for (int mt = 0; mt < 2; ++mt) {
    #pragma unroll
    for (int r = 0; r < 4; ++r) {
      int row = n0 + mt * 16 + q * 4 + r;
      float partial = 0.f;
      if (row < N) {
        #pragma unroll
        for (int nt = 0; nt < 8; ++nt) {
          int col = nt * 16 + ln;
          float o = featsIn[(size_t)row * 128 + col] + acc[mt][nt][r] + bov[nt];
          featsOut[(size_t)row * 128 + col] = o;
          featsOutBf[(size_t)row * 128 + col] = (bf16_t)o;
          partial += o * wfv[nt];
        }
      }
      partial += __shfl_xor(partial, 1);
      partial += __shfl_xor(partial, 2);
      partial += __shfl_xor(partial, 4);
      partial += __shfl_xor(partial, 8);
      if (ln == 0 && row < N) fdot[row] = partial;
    }
  }
}

// ---------------------------------------------------------------------------
// Block-1 update + final projection, fdot form (featsB read replaced by the
// 0.2MB fdot): out[n] = fdot[n] + (pooled[n] @ Wo1 + bo1) . Wf + bf
// ---------------------------------------------------------------------------
__global__ __launch_bounds__(256, 4) void update_final_mfma(
    const float* __restrict__ fdot, const float* __restrict__ pooled,
    const bf16_t* __restrict__ Wopk, const float* __restrict__ bo,
    const float* __restrict__ Wf, const float* __restrict__ bf_,
    float* __restrict__ out, int N)
{
  const int tid  = threadIdx.x;
  const int lane = tid & 63;
  const int w    = tid >> 6;
  const int q    = lane >> 4;
  const int ln   = lane & 15;
  const int n0   = blockIdx.x * 128 + w * 32;

  int r0 = n0 + ln, r1 = n0 + 16 + ln;
  int r0c = (r0 < N) ? r0 : (N - 1);
  int r1c = (r1 < N) ? r1 : (N - 1);
  const float* p0 = pooled + (size_t)r0c * 128 + q * 8;
  const float* p1 = pooled + (size_t)r1c * 128 + q * 8;

  f32x4 acc[2][8];
  #pragma unroll
  for (int mt = 0; mt < 2; ++mt)
    #pragma unroll
    for (int nt = 0; nt < 8; ++nt)
      #pragma unroll
      for (int r = 0; r < 4; ++r) acc[mt][nt][r] = 0.f;

  const bf16x8* Wp = reinterpret_cast<const bf16x8*>(Wopk);
  #pragma unroll
  for (int kt = 0; kt < 4; ++kt) {
    float4 f0a = *reinterpret_cast<const float4*>(p0 + kt * 32);
    float4 f0b = *reinterpret_cast<const float4*>(p0 + kt * 32 + 4);
    float4 f1a = *reinterpret_cast<const float4*>(p1 + kt * 32);
    float4 f1b = *reinterpret_cast<const float4*>(p1 + kt * 32 + 4);
    bf16x8 a0, a1;
    a0[0] = (bf16_t)f0a.x; a0[1] = (bf16_t)f0a.y; a0[2] = (bf16_t)f0a.z; a0[3] = (bf16_t)f0a.w;
    a0[4] = (bf16_t)f0b.x; a0[5] = (bf16_t)f0b.y; a0[6] = (bf16_t)f0b.z; a0[7] = (bf16_t)f0b.w;
    a1[0] = (bf16_t)f1a.x; a1[1] = (bf16_t)f1a.y; a1[2] = (bf16_t)f1a.z; a1[3] = (bf16_t)f1a.w;
    a1[4] = (bf16_t)f1b.x; a1[5] = (bf16_t)f1b.y; a1[6] = (bf16_t)f1b.z; a1[7] = (bf16_t)f1b.w;
    #pragma unroll
    for (int nt = 0; nt < 8; ++nt) {
      bf16x8 bfrag = Wp[(kt * 8 + nt) * 64 + lane];
      acc[0][nt] = __builtin_amdgcn_mfma_f32_16x16x32_bf16(a0, bfrag, acc[0][nt], 0, 0, 0);
      acc[1][nt] = __builtin_amdgcn_mfma_f32_16x16x32_bf16(a1, bfrag, acc[1][nt], 0, 0, 0);
    }
  }

  float bov[8], wfv[8];
  #pragma unroll
  for (int nt = 0; nt < 8; ++nt) { bov[nt] = bo[nt * 16 + ln]; wfv[nt] = Wf[nt * 16 + ln]; }
  float bfs = bf_[0];

  #pragma unroll
  for (int mt = 0; mt < 2; ++mt) {
    #pragma unroll
    for (int r = 0; r < 4; ++r) {
      int row = n0 + mt * 16 + q * 4 + r;
      float partial = 0.f;
      #pragma unroll
      for (int nt = 0; nt < 8; ++nt)
        partial += (acc[mt][nt][r] + bov[nt]) * wfv[nt];
      partial += __shfl_xor(partial, 1);
      partial += __shfl_xor(partial, 2);
      partial += __shfl_xor(partial, 4);
      partial += __shfl_xor(partial, 8);
      if (ln == 0 && row < N) out[row] = partial + fdot[row] + bfs;
    }
  }
}

// ---------------------------------------------------------------------------
extern "C" void kernel_launch(void* const* d_in, const int* in_sizes, int n_in,
                              void* d_out, int out_size, void* d_ws, size_t ws_size,
                              hipStream_t stream)
{
  const float* interpolated = (const float*)d_in[0];
  const float* add_info     = (const float*)d_in[1];
  const int*   nbr          = (const int*)d_in[2];
  const int*   segs         = (const int*)d_in[3];
  const float* Wb0 = (const float*)d_in[4];
  const float* bb0 = (const float*)d_in[5];
  const float* Wo0 = (const float*)d_in[6];
  const float* bo0 = (const float*)d_in[7];
  const float* Wb1 = (const float*)d_in[8];
  const float* bb1 = (const float*)d_in[9];
  const float* Wo1 = (const float*)d_in[10];
  const float* bo1 = (const float*)d_in[11];
  const float* Wf  = (const float*)d_in[12];
  const float* bf_ = (const float*)d_in[13];

  const int N = in_sizes[0] / 128;
  const int E = in_sizes[2];
  float* out = (float*)d_out;

  // workspace layout: BYTE-IDENTICAL to R0/R1 for all existing buffers
  // (edge-health voodoo may be address-sensitive); fdot appended at the end.
  float* pooled = (float*)d_ws;                              // N*128 f32
  float* featsB = pooled + (size_t)N * 128;                  // N*128 f32
  bf16_t* featsB_bf = (bf16_t*)(featsB + (size_t)N * 128);   // N*128 bf16
  bf16_t* Ybf       = featsB_bf + (size_t)N * 128;           // N*128 bf16
  bf16_t* Wtpk0 = Ybf + (size_t)N * 128;                     // 16384
  bf16_t* Wtpk1 = Wtpk0 + 16384;
  bf16_t* Wopk0 = Wtpk1 + 16384;
  bf16_t* Wopk1 = Wopk0 + 16384;
  float*  fdot  = (float*)(Wopk1 + 16384);                   // N f32 (appended)

  const int ugrid = (N + 127) / 128;
  const int egrid = (E + CH * 4 - 1) / (CH * 4);

  // single pack launch for all four 128x128 weights (Wb top rows 0..127, Wo)
  PackArgs pa;
  pa.W[0] = Wb0; pa.P[0] = Wtpk0;
  pa.W[1] = Wb1; pa.P[1] = Wtpk1;
  pa.W[2] = Wo0; pa.P[2] = Wopk0;
  pa.W[3] = Wo1; pa.P[3] = Wopk1;
  pack4_kernel<<<256, 256, 0, stream>>>(pa);

  // block 0
  yproj_f32<<<ugrid, 256, 0, stream>>>(interpolated, Wtpk0, Ybf, pooled, N);
  edge_stream<<<egrid, 256, 0, stream>>>(Ybf, Wb0, bb0, add_info, nbr, segs,
                                         pooled, E);
  update_mfma<<<ugrid, 256, 0, stream>>>(interpolated, pooled, Wopk0, bo0,
                                         Wf, featsB, featsB_bf, fdot, N);

  // block 1
  yproj_bf16<<<ugrid, 256, 0, stream>>>(featsB_bf, Wtpk1, Ybf, pooled, N);
  edge_stream<<<egrid, 256, 0, stream>>>(Ybf, Wb1, bb1, add_info, nbr, segs,
                                         pooled, E);
  update_final_mfma<<<ugrid, 256, 0, stream>>>(fdot, pooled, Wopk1, bo1,
                                               Wf, bf_, out, N);
}